// Round 10
// baseline (114.488 us; speedup 1.0000x reference)
//
#include <hip/hip_runtime.h>
#include <hip/hip_bf16.h>

#define N_HALF 4096
#define M_TOT  8192
#define D      256
#define TTILE  (M_TOT / 256)               // 32 row/col tiles
#define NTILE  (TTILE * (TTILE + 1) / 2)   // 528 lower-triangle tiles
#define NBLK   (NTILE * 4)                 // 2112 single-wave blocks (tile x row-quarter)

typedef __attribute__((ext_vector_type(8))) short bf16x8;
typedef __attribute__((ext_vector_type(4))) float f32x4;
typedef __attribute__((address_space(1))) const unsigned int ga_u32;
typedef __attribute__((address_space(3))) unsigned int ls_u32;

__device__ __forceinline__ float wave_reduce_sum(float v) {
    v += __shfl_xor(v, 1);
    v += __shfl_xor(v, 2);
    v += __shfl_xor(v, 4);
    v += __shfl_xor(v, 8);
    v += __shfl_xor(v, 16);
    v += __shfl_xor(v, 32);
    return v;
}

// Fused: normalize both rows of pair r, positive-pair dot, zero rowsum, zero out.
__global__ void k_prep(const float* __restrict__ zis, const float* __restrict__ zjs,
                       __hip_bfloat16* __restrict__ zn, float* __restrict__ rowsum,
                       float* __restrict__ pos_part, float* __restrict__ out) {
    int r = blockIdx.x;        // 0..4095
    int t = threadIdx.x;       // 0..255
    float zi = zis[(size_t)r * D + t];
    float zj = zjs[(size_t)r * D + t];
    float ssi = wave_reduce_sum(zi * zi);
    float ssj = wave_reduce_sum(zj * zj);
    float dd  = wave_reduce_sum(zi * zj);
    __shared__ float red[3][4];
    int w = t >> 6;
    if ((t & 63) == 0) { red[0][w] = ssi; red[1][w] = ssj; red[2][w] = dd; }
    __syncthreads();
    float ni = fmaxf(sqrtf(red[0][0] + red[0][1] + red[0][2] + red[0][3]), 1e-8f);
    float nj = fmaxf(sqrtf(red[1][0] + red[1][1] + red[1][2] + red[1][3]), 1e-8f);
    zn[(size_t)r * D + t]            = __float2bfloat16(zj / nj);
    zn[(size_t)(r + N_HALF) * D + t] = __float2bfloat16(zi / ni);
    if (t == 0) {
        float dot = red[2][0] + red[2][1] + red[2][2] + red[2][3];
        pos_part[r] = dot / (ni * nj) * 4.0f;   // each unordered pair 2x, /T -> *4
        rowsum[r] = 0.0f;
        rowsum[r + N_HALF] = 0.0f;
        if (r == 0) out[0] = 0.0f;
    }
}

// Symmetric-triangle k_main, WAVE-INDEPENDENT version (round-9 post-mortem:
// k_main ~43us vs ~13-15us max-pipe floor with ALL blocks resident -> the
// residual is the barrier-coupled 2-phase cadence, and shared-pipeline fixes
// failed 3x in rounds 6/7/8). Here every wave is fully independent:
//   - single-wave blocks (64 thr), grid = 528 tiles x 4 row-quarters = 2112
//   - each wave owns 64 i-rows x 256 j-cols; A fragments in regs (as proven)
//   - per j-strip (16 cols): stage 16 zn rows -> OWN 8KB LDS (global_load_lds,
//     same XOR swizzle), own `s_waitcnt vmcnt(0)` + sched_barrier (rule 18),
//     8 ds_read_b128 + 32 MFMA + 16 exp, col-sum flushed DIRECTLY to rowsum
//     (columns unique per strip -> no colsum buffer, no LDS atomics)
//   - ZERO barriers / __syncthreads in the kernel; latency hidden by ~8-12
//     self-paced waves/CU (TLP), which no compiler schedule can defeat.
// Inner arithmetic identical to the round-5/9 proven kernel.
// Off-diag tiles: rowsum[i] row-reduce at end + rowsum[j] col-reduce per strip.
// Diag tiles computed in full, col-side skipped. Exact partition (ex-diag).
__global__ __launch_bounds__(64)
void k_main(const __hip_bfloat16* __restrict__ znh, float* __restrict__ rowsum) {
    __shared__ __align__(16) ushort zs[16 * D];   // 8192 B, private to this wave
    const ushort* zn = reinterpret_cast<const ushort*>(znh);
    int lane = threadIdx.x;   // 0..63
    int q    = lane >> 4;     // quad
    int li   = lane & 15;

    // block decode: tile b (lower triangle, bi <= bj) x row-quarter wq
    int blk = blockIdx.x;
    int b   = blk >> 2;
    int wq  = blk & 3;
    int t = (int)((sqrtf(8.0f * (float)b + 1.0f) - 1.0f) * 0.5f);
    while ((t + 1) * (t + 2) / 2 <= b) ++t;
    while (t * (t + 1) / 2 > b) --t;
    int bj = t;
    int bi = b - t * (t + 1) / 2;
    bool diag = (bi == bj);

    int i_base = bi * 256 + wq * 64;
    int j0     = bj * 256;

    // A fragment (16x16x32 bf16): A[m][k], m = lane&15, k = quad*8 + j
    bf16x8 afrag[4][8];
#pragma unroll
    for (int it = 0; it < 4; ++it) {
        const ushort* ap = zn + (((size_t)(i_base + it * 16 + li)) << 8) + q * 8;
#pragma unroll
        for (int kt = 0; kt < 8; ++kt)
            afrag[it][kt] = *reinterpret_cast<const bf16x8*>(ap + kt * 32);
    }

    float part[4][4];   // [i_tile][reg-row]
#pragma unroll
    for (int it = 0; it < 4; ++it)
#pragma unroll
        for (int r = 0; r < 4; ++r) part[it][r] = 0.0f;

    // Per-lane swizzled ds_read offsets (ushort units): both-sides XOR on 16B
    // units, identical to the proven kernel (strip row = li, r&7 == li&7).
    int koff[8];
    {
        int swsh = (li & 7) << 3;
#pragma unroll
        for (int kt = 0; kt < 8; ++kt)
            koff[kt] = (((kt << 5) | (q << 3)) ^ swsh);
    }

    // 16 strips of 16 j-rows (columns of the sim tile). Single-buffered,
    // self-paced: stage -> own vmcnt(0) -> compute -> own lgkmcnt(0) -> next.
    for (int s = 0; s < 16; ++s) {
        // stage: 8 chunks of 1 KB. Chunk c holds strip-rows 2c,2c+1; lane l
        // writes physical 16B-slot c*64+l: row r = 2c+(l>>5), physical unit
        // pu = l&31 -> fetch logical unit u = pu ^ (r&7) (swizzle source-side).
#pragma unroll
        for (int c = 0; c < 8; ++c) {
            int r = 2 * c + (lane >> 5);
            int u = (lane & 31) ^ (r & 7);
            const ushort* src =
                zn + (((size_t)(j0 + s * 16 + r)) << 8) + (u << 3);
            __builtin_amdgcn_global_load_lds((ga_u32*)src,
                                             (ls_u32*)(zs + c * 512),
                                             16, 0, 0);
        }
        // own staging done (no cross-wave dependency -> no barrier)
        asm volatile("s_waitcnt vmcnt(0)" ::: "memory");
        __builtin_amdgcn_sched_barrier(0);

        f32x4 acc[4] = {{0,0,0,0},{0,0,0,0},{0,0,0,0},{0,0,0,0}};
        const ushort* jrow = zs + li * 256;
#pragma unroll
        for (int kt = 0; kt < 8; ++kt) {
            bf16x8 bfr = *reinterpret_cast<const bf16x8*>(jrow + koff[kt]);
#pragma unroll
            for (int it = 0; it < 4; ++it)
                acc[it] = __builtin_amdgcn_mfma_f32_16x16x32_bf16(
                    afrag[it][kt], bfr, acc[it], 0, 0, 0);
        }
        // C/D layout (m89-verified): col = lane&15, row = quad*4 + reg
        float cs = 0.0f;
#pragma unroll
        for (int it = 0; it < 4; ++it)
#pragma unroll
            for (int r = 0; r < 4; ++r) {
                float e = __expf(acc[it][r] * 2.0f - 2.0f);
                part[it][r] += e;
                cs += e;
            }
        // col-side: sum over this wave's 64 i-rows; columns s*16+li are unique
        // to this strip -> flush straight to global (skip for diagonal tiles).
        cs += __shfl_xor(cs, 16);
        cs += __shfl_xor(cs, 32);
        if (!diag && q == 0) atomicAdd(&rowsum[j0 + s * 16 + li], cs);

        // WAR guard: all ds_reads of this strip retired before re-staging zs.
        asm volatile("s_waitcnt lgkmcnt(0)" ::: "memory");
        __builtin_amdgcn_sched_barrier(0);
    }

    // Row-side: reduce across the 16 lanes holding different j-cols of the same rows.
#pragma unroll
    for (int it = 0; it < 4; ++it)
#pragma unroll
        for (int r = 0; r < 4; ++r) {
            float v = part[it][r];
            v += __shfl_xor(v, 1);
            v += __shfl_xor(v, 2);
            v += __shfl_xor(v, 4);
            v += __shfl_xor(v, 8);
            if (li == 0) atomicAdd(&rowsum[i_base + it * 16 + q * 4 + r], v);
        }
}

// lse_i = 2 + log(rowsum_i - 1); loss = (sum lse - sum pos)/M.
// 32 blocks; per-block partial -> atomicAdd into pre-zeroed out[0].
__global__ void k_final(const float* __restrict__ rowsum, const float* __restrict__ pos_part,
                        float* __restrict__ out) {
    int idx = blockIdx.x * 256 + threadIdx.x;   // 0..8191
    float acc  = 2.0f + __logf(rowsum[idx] - 1.0f);
    float pacc = (idx < N_HALF) ? pos_part[idx] : 0.0f;
    acc  = wave_reduce_sum(acc);
    pacc = wave_reduce_sum(pacc);
    __shared__ float wsum[4], psum[4];
    int t = threadIdx.x;
    if ((t & 63) == 0) { wsum[t >> 6] = acc; psum[t >> 6] = pacc; }
    __syncthreads();
    if (t == 0) {
        float tot = wsum[0] + wsum[1] + wsum[2] + wsum[3]
                  - (psum[0] + psum[1] + psum[2] + psum[3]);
        atomicAdd(out, tot / (float)M_TOT);
    }
}

extern "C" void kernel_launch(void* const* d_in, const int* in_sizes, int n_in,
                              void* d_out, int out_size, void* d_ws, size_t ws_size,
                              hipStream_t stream) {
    const float* zis = (const float*)d_in[0];
    const float* zjs = (const float*)d_in[1];
    char* ws = (char*)d_ws;
    __hip_bfloat16* zn = (__hip_bfloat16*)ws;                         // 4 MB
    float* rowsum   = (float*)(ws + (size_t)M_TOT * D * 2);           // 32 KB
    float* pos_part = rowsum + M_TOT;                                 // 16 KB
    float* out = (float*)d_out;

    k_prep<<<N_HALF, 256, 0, stream>>>(zis, zjs, zn, rowsum, pos_part, out);
    k_main<<<NBLK, 64, 0, stream>>>(zn, rowsum);
    k_final<<<M_TOT / 256, 256, 0, stream>>>(rowsum, pos_part, out);
}